// Round 11
// baseline (465.217 us; speedup 1.0000x reference)
//
#include <hip/hip_runtime.h>
#include <stdint.h>
#include <stdio.h>

#define B_   2
#define T_   1024
#define C_   1024
#define H_   4096
#define ER_  8
#define ES_  2
#define NTOK (B_*T_)   // 2048

typedef __attribute__((ext_vector_type(4))) float  f32x4;
typedef __attribute__((ext_vector_type(8))) __bf16 bf16x8;
typedef __attribute__((ext_vector_type(8))) unsigned short us8;

__device__ __forceinline__ unsigned short f2bf(float f) {
  unsigned u = __builtin_bit_cast(unsigned, f);
  u += 0x7FFFu + ((u >> 16) & 1u);          // RNE
  return (unsigned short)(u >> 16);
}
__device__ __forceinline__ float bf2f(unsigned short s) {
  unsigned u = (unsigned)s << 16;
  return __builtin_bit_cast(float, u);
}

__device__ __forceinline__ void async_ld16(void* lds, const void* g) {
  __builtin_amdgcn_global_load_lds(
      (const __attribute__((address_space(1))) char*)(uintptr_t)g,
      (__attribute__((address_space(3))) char*)(uintptr_t)lds, 16, 0, 0);
}

__device__ __forceinline__ f32x4 mfma16(bf16x8 a, bf16x8 b, f32x4 c) {
  return __builtin_amdgcn_mfma_f32_16x16x32_bf16(a, b, c, 0, 0, 0);
}

// fast exact-enough GELU: tanh form, max |err| vs erf-GELU ~3e-3
__device__ __forceinline__ float gelu_f(float v) {
  float inner = 0.7978845608f * v * (1.0f + 0.044715f * v * v);
  float e = __expf(2.0f * inner);
  return v * (1.0f - __builtin_amdgcn_rcpf(e + 1.0f));
}

// -------------------------------------------- per-token norm scales + routing
__global__ void k_prep(const float* __restrict__ u, const float* __restrict__ gs,
                       const float* __restrict__ gr, const float* __restrict__ cent,
                       __bf16* __restrict__ xns, __bf16* __restrict__ xnr,
                       int* __restrict__ tki, float* __restrict__ tkg)
{
  const int t = blockIdx.x, tid = threadIdx.x;
  float4 v = reinterpret_cast<const float4*>(u + (size_t)t * C_)[tid];
  float ss = v.x*v.x + v.y*v.y + v.z*v.z + v.w*v.w;
  const int c0 = tid * 4;
  float sc[ER_];
  #pragma unroll
  for (int e = 0; e < ER_; ++e) {
    sc[e] = v.x * cent[(c0+0)*ER_ + e] + v.y * cent[(c0+1)*ER_ + e]
          + v.z * cent[(c0+2)*ER_ + e] + v.w * cent[(c0+3)*ER_ + e];
  }
  #pragma unroll
  for (int o = 32; o > 0; o >>= 1) {
    ss += __shfl_down(ss, o);
    #pragma unroll
    for (int e = 0; e < ER_; ++e) sc[e] += __shfl_down(sc[e], o);
  }
  __shared__ float red[4][ER_ + 1];
  __shared__ float sbc;
  const int w = tid >> 6;
  if ((tid & 63) == 0) {
    red[w][0] = ss;
    #pragma unroll
    for (int e = 0; e < ER_; ++e) red[w][1 + e] = sc[e];
  }
  __syncthreads();
  if (tid == 0) {
    float S = red[0][0] + red[1][0] + red[2][0] + red[3][0];
    sbc = rsqrtf(S * (1.0f / C_) + 1.1920929e-07f);
    float p[ER_]; float psum = 0.f;
    #pragma unroll
    for (int e = 0; e < ER_; ++e) {
      float d = red[0][1+e] + red[1][1+e] + red[2][1+e] + red[3][1+e];
      p[e] = 1.f / (1.f + expf(-d));
      psum += p[e];
    }
    int i0 = 0;
    for (int e = 1; e < ER_; ++e) if (p[e] > p[i0]) i0 = e;
    int i1 = -1;
    for (int e = 0; e < ER_; ++e) { if (e == i0) continue; if (i1 < 0 || p[e] > p[i1]) i1 = e; }
    tki[t*2+0] = i0;  tki[t*2+1] = i1;
    tkg[t*2+0] = p[i0] / psum;  tkg[t*2+1] = p[i1] / psum;
  }
  __syncthreads();
  const float s = sbc;
  ushort4 os, orr;
  os.x  = f2bf(v.x * s * gs[c0+0]); os.y  = f2bf(v.y * s * gs[c0+1]);
  os.z  = f2bf(v.z * s * gs[c0+2]); os.w  = f2bf(v.w * s * gs[c0+3]);
  orr.x = f2bf(v.x * s * gr[c0+0]); orr.y = f2bf(v.y * s * gr[c0+1]);
  orr.z = f2bf(v.z * s * gr[c0+2]); orr.w = f2bf(v.w * s * gr[c0+3]);
  reinterpret_cast<ushort4*>(xns)[(size_t)t * (C_/4) + tid] = os;
  reinterpret_cast<ushort4*>(xnr)[(size_t)t * (C_/4) + tid] = orr;
}

// ------------------------------ expert token-list builder (+ inverse mapping)
__global__ void k_build(const int* __restrict__ tki, const float* __restrict__ tkg,
                        int* __restrict__ listTok, float* __restrict__ listGate,
                        int* __restrict__ offs, int* __restrict__ cnts,
                        int* __restrict__ inv)
{
  __shared__ int cnt[ER_], cur[ER_], off[ER_];
  const int tid = threadIdx.x;
  if (tid < ER_) cnt[tid] = 0;
  __syncthreads();
  for (int i = tid; i < NTOK*2; i += 256) atomicAdd(&cnt[tki[i]], 1);
  __syncthreads();
  if (tid == 0) {
    int a = 0;
    for (int e = 0; e < ER_; ++e) { off[e] = a; cur[e] = a; a += cnt[e]; }
  }
  __syncthreads();
  for (int i = tid; i < NTOK*2; i += 256) {
    int e = tki[i];
    int p = atomicAdd(&cur[e], 1);
    listTok[p]  = i >> 1;
    listGate[p] = tkg[i];
    inv[i] = p;
  }
  if (tid < ER_) { offs[tid] = off[tid]; cnts[tid] = cnt[tid]; }
}

// ---------------- weight transpose + fp32->bf16 ([K][N] -> [N][K]), bf16 LDS
__global__ void k_convT(const float* __restrict__ src, __bf16* __restrict__ dst,
                        int K, int N)
{
  const int e = blockIdx.z;
  src += (size_t)e * K * N;
  unsigned short* d = reinterpret_cast<unsigned short*>(dst) + (size_t)e * K * N;
  const int n0 = blockIdx.x * 64, k0 = blockIdx.y * 64;
  __shared__ unsigned short tb[64][72];
  const int tid = threadIdx.x;
  const int kr = tid >> 4, c4 = (tid & 15) * 4;
  #pragma unroll
  for (int i = 0; i < 4; ++i) {
    const int kk = kr + i * 16;
    float4 v = *reinterpret_cast<const float4*>(&src[(size_t)(k0+kk)*N + n0 + c4]);
    tb[kk][c4+0] = f2bf(v.x); tb[kk][c4+1] = f2bf(v.y);
    tb[kk][c4+2] = f2bf(v.z); tb[kk][c4+3] = f2bf(v.w);
  }
  __syncthreads();
  const int nr = tid >> 2;
  #pragma unroll
  for (int j = 0; j < 2; ++j) {
    const int kc = ((tid & 3) + j * 4) * 8;
    us8 o;
    #pragma unroll
    for (int t2 = 0; t2 < 8; ++t2) o[t2] = tb[kc + t2][nr];
    *reinterpret_cast<us8*>(&d[(size_t)(n0+nr)*K + k0 + kc]) = o;
  }
}

// ------------------------------------------------------------- fused GEMM
// 256x256 tile, BK=32, 8 waves (2m x 4n), 512 threads.
// 8-PHASE-STYLE INTERLEAVED PIPELINE (m198/m201 mechanism, adapted):
//   3 LDS slots (96 KB), 2-tile prefetch stagger. Per tile t, 2 phases:
//   ph0: {ds_read af[0-3]+bfr[0-3] | stage A of tile t+2 (2 gload)}
//        barrier; lgkmcnt(0); setprio(1); 16 MFMA; setprio(0); barrier
//   ph1: {ds_read af[4-7] | stage B of tile t+2 (2 gload)}
//        barrier; lgkmcnt(0); setprio(1); 16 MFMA; setprio(0);
//        vmcnt(4) [allow t+2's 4 loads in flight; t+1 guaranteed landed];
//        barrier
// Loads issued >=4 phases (~1600cy) before use -> latency covered; DMA fed
// continuously (2 gloads/wave/phase) instead of burst-8-then-drain.
// [R10 post-mortem: wall time = staged_bytes/1KB x ~234cy/256CU across ALL
//  prior variants -> per-CU gload_lds service rate is the limiter; m198's
//  interleave measured ~69cy/gload.]
// Slot safety: compute(t) reads slot t%3; stage(t+2) writes slot (t+2)%3
// (≠ t%3, ≠ (t+1)%3); slot's previous reader (tile t-1) fully barriered out.
struct GP {
  const __bf16 *xns, *xnr, *hids, *hidr, *wts, *wtr;
  const float *b1s, *b1r, *b2s, *b2r;
  __bf16 *hidws, *hidwr;
  unsigned short *psh, *prt;      // bf16 partials
  const int* listTok; const float* listGate; const int* offs; const int* cnts;
};

template<int PHASE>
__global__ __launch_bounds__(512)
void k_gemm(GP p)
{
  const int z  = blockIdx.z;
  const int xb = blockIdx.x;    // n-block
  const int yb = blockIdx.y;    // m-block

  int M, slotbase = 0, kbase = 0, NT, rowmode;   // 0=dense 1=listTok 2=slot
  long KD;
  const __bf16 *Ab, *Wb;
  const float* bias = nullptr;
  __bf16* hb = nullptr; int hstride = 0;
  unsigned short* pout = nullptr;
  int eidx = 0;

  if (PHASE == 1) {
    KD = C_; NT = C_ / 32;
    if (z < ES_) {
      M = NTOK; rowmode = 0; Ab = p.xns;
      Wb = p.wts + (size_t)z * H_ * C_;
      bias = p.b1s + z * H_;
      hb = p.hidws + z * H_; hstride = ES_ * H_;
    } else {
      eidx = z - ES_;
      M = p.cnts[eidx]; slotbase = p.offs[eidx]; rowmode = 1; Ab = p.xnr;
      Wb = p.wtr + (size_t)eidx * H_ * C_;
      bias = p.b1r + eidx * H_;
      hb = p.hidwr + (size_t)slotbase * H_; hstride = H_;
    }
  } else {
    if (z < 4) {
      const int kc = z;
      M = NTOK; rowmode = 0; Ab = p.hids; KD = ES_ * H_;
      kbase = kc * 2048; NT = 2048 / 32;
      Wb = p.wts; bias = (kc == 0) ? p.b2s : nullptr;
      pout = p.psh + (size_t)kc * NTOK * C_;
    } else {
      const int zz = z - 4;
      eidx = zz >> 1; const int kc = zz & 1;
      M = p.cnts[eidx]; slotbase = p.offs[eidx]; rowmode = 2; Ab = p.hidr; KD = H_;
      kbase = kc * 2048; NT = 2048 / 32;
      Wb = p.wtr + (size_t)eidx * C_ * H_;
      bias = (kc == 0) ? (p.b2r + eidx * C_) : nullptr;
      pout = p.prt + (size_t)kc * (NTOK*2) * C_ + (size_t)slotbase * C_;
    }
  }

  const int m0 = yb * 256;
  if (m0 >= M) return;
  const int n0 = xb * 256;

  const int tid = threadIdx.x;
  const int w = tid >> 6, l = tid & 63;

  __shared__ __align__(16) __bf16 Al[3 * 256 * 32];   // 48 KB
  __shared__ __align__(16) __bf16 Bl[3 * 256 * 32];   // 48 KB

  // staging: tile slice = 16 KB (256 rows x 32 k x 2B, 64B rows), 2 block-wide
  // gload instrs; instr i covers rows i*128 + (tid>>2); thread chunk (tid&3),
  // source k-chunk XOR-swizzled by row&3; LDS dest linear (rule 21).
  const int srow = tid >> 2;                              // 0..127
  const int schunk = ((tid & 3) ^ (srow & 3)) * 8;        // elems
  const __bf16* aptr[2];
  const __bf16* bptr[2];
  #pragma unroll
  for (int i = 0; i < 2; ++i) {
    int rr = i * 128 + srow;
    int ra = m0 + rr; if (ra >= M) ra = M - 1;
    size_t arow;
    if (rowmode == 0)      arow = (size_t)ra;
    else if (rowmode == 1) arow = (size_t)p.listTok[slotbase + ra];
    else                   arow = (size_t)(slotbase + ra);
    aptr[i] = Ab + arow * KD + kbase + schunk;
    bptr[i] = Wb + (size_t)(n0 + rr) * KD + kbase + schunk;
  }

  auto stageA = [&](int t) {
    char* ab = (char*)Al + (t % 3) * 16384 + w * 1024;
    async_ld16(ab,        aptr[0] + t * 32);
    async_ld16(ab + 8192, aptr[1] + t * 32);
  };
  auto stageB = [&](int t) {
    char* bb = (char*)Bl + (t % 3) * 16384 + w * 1024;
    async_ld16(bb,        bptr[0] + t * 32);
    async_ld16(bb + 8192, bptr[1] + t * 32);
  };

  // fragment geometry: wave (w>>2) m-half (128 rows), (w&3) n-quarter (64)
  const int wm = (w >> 2) * 128;
  const int wn = (w & 3) * 64;
  const int lr = l & 15, qh = l >> 4;
  // LDS read: row r, k-quarter qh -> byte r*64 + ((qh ^ (r&3))*16); r&3 == lr&3
  const int rchunk = (qh ^ (lr & 3)) * 16;

  f32x4 acc[8][4];
  #pragma unroll
  for (int m = 0; m < 8; ++m)
    #pragma unroll
    for (int n = 0; n < 4; ++n) acc[m][n] = (f32x4){0.f, 0.f, 0.f, 0.f};

  // ---- prologue: stage tiles 0,1; wait tile 0 (vmcnt(4): tile 1 in flight)
  stageA(0); stageB(0);
  if (NT > 1) {
    stageA(1); stageB(1);
    asm volatile("s_waitcnt vmcnt(4)" ::: "memory");
  } else {
    asm volatile("s_waitcnt vmcnt(0)" ::: "memory");
  }
  __builtin_amdgcn_s_barrier();

  for (int t = 0; t < NT; ++t) {
    const char* As = (const char*)Al + (t % 3) * 16384;
    const char* Bs = (const char*)Bl + (t % 3) * 16384;
    bf16x8 af0[4], af1[4], bfr[4];
    // ---- ph0: read quadrant regs + stage A(t+2) ----
    #pragma unroll
    for (int m = 0; m < 4; ++m)
      af0[m] = *reinterpret_cast<const bf16x8*>(As + (wm + m*16 + lr) * 64 + rchunk);
    #pragma unroll
    for (int n = 0; n < 4; ++n)
      bfr[n] = *reinterpret_cast<const bf16x8*>(Bs + (wn + n*16 + lr) * 64 + rchunk);
    if (t + 2 < NT) stageA(t + 2);
    __builtin_amdgcn_s_barrier();
    asm volatile("s_waitcnt lgkmcnt(0)" ::: "memory");
    __builtin_amdgcn_s_setprio(1);
    #pragma unroll
    for (int m = 0; m < 4; ++m)
      #pragma unroll
      for (int n = 0; n < 4; ++n)
        acc[m][n] = mfma16(af0[m], bfr[n], acc[m][n]);
    __builtin_amdgcn_s_setprio(0);
    __builtin_amdgcn_s_barrier();
    // ---- ph1: read af[4-7] + stage B(t+2) ----
    #pragma unroll
    for (int m = 0; m < 4; ++m)
      af1[m] = *reinterpret_cast<const bf16x8*>(As + (wm + (m+4)*16 + lr) * 64 + rchunk);
    if (t + 2 < NT) stageB(t + 2);
    __builtin_amdgcn_s_barrier();
    asm volatile("s_waitcnt lgkmcnt(0)" ::: "memory");
    __builtin_amdgcn_s_setprio(1);
    #pragma unroll
    for (int m = 0; m < 4; ++m)
      #pragma unroll
      for (int n = 0; n < 4; ++n)
        acc[m+4][n] = mfma16(af1[m], bfr[n], acc[m+4][n]);
    __builtin_amdgcn_s_setprio(0);
    // boundary: guarantee tile t+1 landed; allow tile t+2's 4 loads in flight
    if (t + 2 < NT) asm volatile("s_waitcnt vmcnt(4)" ::: "memory");
    else            asm volatile("s_waitcnt vmcnt(0)" ::: "memory");
    __builtin_amdgcn_s_barrier();
  }

  // ---- epilogue — C/D layout: col = lane&15, row = (lane>>4)*4 + reg ----
  #pragma unroll
  for (int mf = 0; mf < 8; ++mf) {
    const int rbase = m0 + wm + mf*16 + qh * 4;
    #pragma unroll
    for (int rg = 0; rg < 4; ++rg) {
      const int r = rbase + rg;
      if (r >= M) continue;
      if constexpr (PHASE == 1) {
        #pragma unroll
        for (int nf = 0; nf < 4; ++nf) {
          const int col = n0 + wn + nf*16 + lr;
          float v = acc[mf][nf][rg] + bias[col];
          reinterpret_cast<unsigned short*>(hb)[(size_t)r * hstride + col] =
              f2bf(gelu_f(v));
        }
      } else {
        #pragma unroll
        for (int nf = 0; nf < 4; ++nf) {
          const int col = n0 + wn + nf*16 + lr;
          float v = acc[mf][nf][rg];
          if (bias) v += bias[col];
          pout[(size_t)r * C_ + col] = f2bf(v);
        }
      }
    }
  }
}

// ------------------------------------------- final fuse: out = u + sh + routed
__global__ void k_fuse(const float* __restrict__ u,
                       const unsigned short* __restrict__ psh,
                       const unsigned short* __restrict__ prt,
                       const int* __restrict__ inv, const float* __restrict__ tkg,
                       float* __restrict__ out)
{
  const int t = blockIdx.x, tid = threadIdx.x;
  const int c = tid * 4;
  const int s0 = inv[t*2], s1 = inv[t*2+1];
  const float g0 = tkg[t*2], g1 = tkg[t*2+1];
  float4 a = reinterpret_cast<const float4*>(u + (size_t)t * C_)[tid];
  float r[4] = {a.x, a.y, a.z, a.w};
  #pragma unroll
  for (int kc = 0; kc < 4; ++kc) {
    ushort4 q = *reinterpret_cast<const ushort4*>(&psh[((size_t)kc * NTOK + t) * C_ + c]);
    r[0] += bf2f(q.x); r[1] += bf2f(q.y); r[2] += bf2f(q.z); r[3] += bf2f(q.w);
  }
  #pragma unroll
  for (int k = 0; k < 2; ++k) {
    const int s = k ? s1 : s0;
    const float g = k ? g1 : g0;
    ushort4 q0 = *reinterpret_cast<const ushort4*>(&prt[(size_t)s * C_ + c]);
    ushort4 q1 = *reinterpret_cast<const ushort4*>(&prt[((size_t)(NTOK*2) + s) * C_ + c]);
    r[0] += g * (bf2f(q0.x) + bf2f(q1.x));
    r[1] += g * (bf2f(q0.y) + bf2f(q1.y));
    r[2] += g * (bf2f(q0.z) + bf2f(q1.z));
    r[3] += g * (bf2f(q0.w) + bf2f(q1.w));
  }
  float4 o = {r[0], r[1], r[2], r[3]};
  reinterpret_cast<float4*>(out + (size_t)t * C_)[tid] = o;
}

// -----------------------------------------------------------------------------
extern "C" void kernel_launch(void* const* d_in, const int* in_sizes, int n_in,
                              void* d_out, int out_size, void* d_ws, size_t ws_size,
                              hipStream_t stream)
{
  const float* u    = (const float*)d_in[0];
  const float* gs   = (const float*)d_in[1];
  const float* W1s  = (const float*)d_in[2];
  const float* b1s  = (const float*)d_in[3];
  const float* W2s  = (const float*)d_in[4];
  const float* b2s  = (const float*)d_in[5];
  const float* gr   = (const float*)d_in[6];
  const float* W1r  = (const float*)d_in[7];
  const float* b1r  = (const float*)d_in[8];
  const float* W2r  = (const float*)d_in[9];
  const float* b2r  = (const float*)d_in[10];
  const float* cent = (const float*)d_in[11];
  float* out = (float*)d_out;

  char* ws = (char*)d_ws;
  size_t off = 0;
  auto alloc = [&](size_t bytes) -> char* {
    char* p = ws + off;
    off += (bytes + 255) & ~(size_t)255;
    return p;
  };
  __bf16* wbuf = (__bf16*)alloc((size_t)(ES_ + ER_) * H_ * C_ * 2);  // 84 MB
  __bf16* xns  = (__bf16*)alloc((size_t)NTOK * C_ * 2);
  __bf16* xnr  = (__bf16*)alloc((size_t)NTOK * C_ * 2);
  __bf16* hids = (__bf16*)alloc((size_t)NTOK * (ES_*H_) * 2);        // 33.5 MB
  __bf16* hidr = (__bf16*)alloc((size_t)NTOK * 2 * H_ * 2);          // 33.5 MB
  unsigned short* psh = (unsigned short*)alloc((size_t)4 * NTOK * C_ * 2);    // 16.8 MB
  unsigned short* prt = (unsigned short*)alloc((size_t)2 * NTOK*2 * C_ * 2);  // 16.8 MB
  int*    tki      = (int*)  alloc(NTOK * 2 * 4);
  float*  tkg      = (float*)alloc(NTOK * 2 * 4);
  int*    listTok  = (int*)  alloc(NTOK * 2 * 4);
  float*  listGate = (float*)alloc(NTOK * 2 * 4);
  int*    inv      = (int*)  alloc(NTOK * 2 * 4);
  int*    offs     = (int*)  alloc(64);
  int*    cnts     = (int*)  alloc(64);
  if (off > ws_size) {
    fprintf(stderr, "ATHENA: WORKSPACE TOO SMALL: need %zu bytes, have %zu\n", off, ws_size);
    return;
  }

  __bf16* wt_s = wbuf;
  __bf16* wt_r = wbuf + (size_t)ES_ * H_ * C_;

  GP p;
  p.xns = xns; p.xnr = xnr; p.hids = hids; p.hidr = hidr;
  p.wts = wt_s; p.wtr = wt_r;
  p.b1s = b1s; p.b1r = b1r; p.b2s = b2s; p.b2r = b2r;
  p.hidws = hids; p.hidwr = hidr;
  p.psh = psh; p.prt = prt;
  p.listTok = listTok; p.listGate = listGate; p.offs = offs; p.cnts = cnts;

  k_prep<<<dim3(NTOK), dim3(256), 0, stream>>>(u, gs, gr, cent, xns, xnr, tki, tkg);
  k_build<<<dim3(1), dim3(256), 0, stream>>>(tki, tkg, listTok, listGate, offs, cnts, inv);

  // W1 [E][C][H] -> bf16 [E*H][C]
  k_convT<<<dim3(H_/64, C_/64, ES_), dim3(256), 0, stream>>>(W1s, wt_s, C_, H_);
  k_convT<<<dim3(H_/64, C_/64, ER_), dim3(256), 0, stream>>>(W1r, wt_r, C_, H_);

  // fused GEMM1: z = {2 shared, 8 routed}; x = 16 n-blocks, y = 8 m-blocks
  k_gemm<1><<<dim3(16, 8, ES_ + ER_), dim3(512), 0, stream>>>(p);

  // W2: shared stacked [2H][C] -> [C][2H]; routed per-expert [H][C] -> [C][H]
  k_convT<<<dim3(C_/64, (ES_*H_)/64, 1), dim3(256), 0, stream>>>(W2s, wt_s, ES_*H_, C_);
  k_convT<<<dim3(C_/64, H_/64, ER_), dim3(256), 0, stream>>>(W2r, wt_r, H_, C_);

  // fused GEMM2 -> bf16 partials (no atomics): z = {4 shared kc, 16 routed (e,kc)}
  k_gemm<2><<<dim3(4, 8, 4 + ER_*2), dim3(512), 0, stream>>>(p);

  // fuse: out = u + sum(psh) + g0*(prt0+prt1)[s0] + g1*(prt0+prt1)[s1]
  k_fuse<<<dim3(NTOK), dim3(256), 0, stream>>>(u, psh, prt, inv, tkg, out);
}

// Round 12
// 365.346 us; speedup vs baseline: 1.2734x; 1.2734x over previous
//
#include <hip/hip_runtime.h>
#include <stdint.h>
#include <stdio.h>

#define B_   2
#define T_   1024
#define C_   1024
#define H_   4096
#define ER_  8
#define ES_  2
#define NTOK (B_*T_)   // 2048

typedef __attribute__((ext_vector_type(4))) float  f32x4;
typedef __attribute__((ext_vector_type(8))) __bf16 bf16x8;
typedef __attribute__((ext_vector_type(8))) unsigned short us8;

__device__ __forceinline__ unsigned short f2bf(float f) {
  unsigned u = __builtin_bit_cast(unsigned, f);
  u += 0x7FFFu + ((u >> 16) & 1u);          // RNE
  return (unsigned short)(u >> 16);
}
__device__ __forceinline__ float bf2f(unsigned short s) {
  unsigned u = (unsigned)s << 16;
  return __builtin_bit_cast(float, u);
}

__device__ __forceinline__ void async_ld16(void* lds, const void* g) {
  __builtin_amdgcn_global_load_lds(
      (const __attribute__((address_space(1))) char*)(uintptr_t)g,
      (__attribute__((address_space(3))) char*)(uintptr_t)lds, 16, 0, 0);
}

__device__ __forceinline__ f32x4 mfma16(bf16x8 a, bf16x8 b, f32x4 c) {
  return __builtin_amdgcn_mfma_f32_16x16x32_bf16(a, b, c, 0, 0, 0);
}

// fast exact-enough GELU: tanh form, max |err| vs erf-GELU ~3e-3
__device__ __forceinline__ float gelu_f(float v) {
  float inner = 0.7978845608f * v * (1.0f + 0.044715f * v * v);
  float e = __expf(2.0f * inner);
  return v * (1.0f - __builtin_amdgcn_rcpf(e + 1.0f));
}

// -------------------------------------------- per-token norm scales + routing
__global__ void k_prep(const float* __restrict__ u, const float* __restrict__ gs,
                       const float* __restrict__ gr, const float* __restrict__ cent,
                       __bf16* __restrict__ xns, __bf16* __restrict__ xnr,
                       int* __restrict__ tki, float* __restrict__ tkg)
{
  const int t = blockIdx.x, tid = threadIdx.x;
  float4 v = reinterpret_cast<const float4*>(u + (size_t)t * C_)[tid];
  float ss = v.x*v.x + v.y*v.y + v.z*v.z + v.w*v.w;
  const int c0 = tid * 4;
  float sc[ER_];
  #pragma unroll
  for (int e = 0; e < ER_; ++e) {
    sc[e] = v.x * cent[(c0+0)*ER_ + e] + v.y * cent[(c0+1)*ER_ + e]
          + v.z * cent[(c0+2)*ER_ + e] + v.w * cent[(c0+3)*ER_ + e];
  }
  #pragma unroll
  for (int o = 32; o > 0; o >>= 1) {
    ss += __shfl_down(ss, o);
    #pragma unroll
    for (int e = 0; e < ER_; ++e) sc[e] += __shfl_down(sc[e], o);
  }
  __shared__ float red[4][ER_ + 1];
  __shared__ float sbc;
  const int w = tid >> 6;
  if ((tid & 63) == 0) {
    red[w][0] = ss;
    #pragma unroll
    for (int e = 0; e < ER_; ++e) red[w][1 + e] = sc[e];
  }
  __syncthreads();
  if (tid == 0) {
    float S = red[0][0] + red[1][0] + red[2][0] + red[3][0];
    sbc = rsqrtf(S * (1.0f / C_) + 1.1920929e-07f);
    float p[ER_]; float psum = 0.f;
    #pragma unroll
    for (int e = 0; e < ER_; ++e) {
      float d = red[0][1+e] + red[1][1+e] + red[2][1+e] + red[3][1+e];
      p[e] = 1.f / (1.f + expf(-d));
      psum += p[e];
    }
    int i0 = 0;
    for (int e = 1; e < ER_; ++e) if (p[e] > p[i0]) i0 = e;
    int i1 = -1;
    for (int e = 0; e < ER_; ++e) { if (e == i0) continue; if (i1 < 0 || p[e] > p[i1]) i1 = e; }
    tki[t*2+0] = i0;  tki[t*2+1] = i1;
    tkg[t*2+0] = p[i0] / psum;  tkg[t*2+1] = p[i1] / psum;
  }
  __syncthreads();
  const float s = sbc;
  ushort4 os, orr;
  os.x  = f2bf(v.x * s * gs[c0+0]); os.y  = f2bf(v.y * s * gs[c0+1]);
  os.z  = f2bf(v.z * s * gs[c0+2]); os.w  = f2bf(v.w * s * gs[c0+3]);
  orr.x = f2bf(v.x * s * gr[c0+0]); orr.y = f2bf(v.y * s * gr[c0+1]);
  orr.z = f2bf(v.z * s * gr[c0+2]); orr.w = f2bf(v.w * s * gr[c0+3]);
  reinterpret_cast<ushort4*>(xns)[(size_t)t * (C_/4) + tid] = os;
  reinterpret_cast<ushort4*>(xnr)[(size_t)t * (C_/4) + tid] = orr;
}

// ------------------------------ expert token-list builder (+ inverse mapping)
__global__ void k_build(const int* __restrict__ tki, const float* __restrict__ tkg,
                        int* __restrict__ listTok, float* __restrict__ listGate,
                        int* __restrict__ offs, int* __restrict__ cnts,
                        int* __restrict__ inv)
{
  __shared__ int cnt[ER_], cur[ER_], off[ER_];
  const int tid = threadIdx.x;
  if (tid < ER_) cnt[tid] = 0;
  __syncthreads();
  for (int i = tid; i < NTOK*2; i += 256) atomicAdd(&cnt[tki[i]], 1);
  __syncthreads();
  if (tid == 0) {
    int a = 0;
    for (int e = 0; e < ER_; ++e) { off[e] = a; cur[e] = a; a += cnt[e]; }
  }
  __syncthreads();
  for (int i = tid; i < NTOK*2; i += 256) {
    int e = tki[i];
    int p = atomicAdd(&cur[e], 1);
    listTok[p]  = i >> 1;
    listGate[p] = tkg[i];
    inv[i] = p;
  }
  if (tid < ER_) { offs[tid] = off[tid]; cnts[tid] = cnt[tid]; }
}

// ---------------- weight transpose + fp32->bf16 ([K][N] -> [N][K]), bf16 LDS
__global__ void k_convT(const float* __restrict__ src, __bf16* __restrict__ dst,
                        int K, int N)
{
  const int e = blockIdx.z;
  src += (size_t)e * K * N;
  unsigned short* d = reinterpret_cast<unsigned short*>(dst) + (size_t)e * K * N;
  const int n0 = blockIdx.x * 64, k0 = blockIdx.y * 64;
  __shared__ unsigned short tb[64][72];
  const int tid = threadIdx.x;
  const int kr = tid >> 4, c4 = (tid & 15) * 4;
  #pragma unroll
  for (int i = 0; i < 4; ++i) {
    const int kk = kr + i * 16;
    float4 v = *reinterpret_cast<const float4*>(&src[(size_t)(k0+kk)*N + n0 + c4]);
    tb[kk][c4+0] = f2bf(v.x); tb[kk][c4+1] = f2bf(v.y);
    tb[kk][c4+2] = f2bf(v.z); tb[kk][c4+3] = f2bf(v.w);
  }
  __syncthreads();
  const int nr = tid >> 2;
  #pragma unroll
  for (int j = 0; j < 2; ++j) {
    const int kc = ((tid & 3) + j * 4) * 8;
    us8 o;
    #pragma unroll
    for (int t2 = 0; t2 < 8; ++t2) o[t2] = tb[kc + t2][nr];
    *reinterpret_cast<us8*>(&d[(size_t)(n0+nr)*K + k0 + kc]) = o;
  }
}

// ------------------------------------------------------------- fused GEMM
// 128x128 tile, BK=32, 4 waves (2m x 2n), 256 threads, double-buffered 32KB
// LDS, __launch_bounds__(256,4) -> 4 blocks/CU co-resident (m97/m114
// mechanism: co-resident blocks overlap each other's staging drains — the
// ONLY thing that has moved cyc/gload in 11 rounds: 1 blk=234cy, 1.4=161,
// 3 (m97)=~45-75).  Clean r10 loop: stage(next) -> compute(cur) -> ONE
// __syncthreads per tile. No asm, no sched_barrier, no setprio.
// LDS swizzle: 64B rows, chunk = qh ^ ((lr>>1)&3) read / matching source
// pre-swizzle (rule 21) -> max 2-way bank alias = free (m136).
// PHASE 1: z<2  shared expert z (dense, N=H)  -> hids cols z*H   (gelu, bf16)
//          z>=2 routed e=z-2 (gathered)       -> hidr slots      (gelu, bf16)
// PHASE 2: z<4  shared kc=z (K-chunk 2048 of 8192): psh[kc] = acc (+b2s @kc0)
//          z>=4 routed (e,kc)=((z-4)>>1,(z-4)&1), K-chunk 2048 of 4096:
//               prt[kc][slot] = acc (+b2r[e] @kc0); bf16 partials, no atomics
struct GP {
  const __bf16 *xns, *xnr, *hids, *hidr, *wts, *wtr;
  const float *b1s, *b1r, *b2s, *b2r;
  __bf16 *hidws, *hidwr;
  unsigned short *psh, *prt;      // bf16 partials
  const int* listTok; const float* listGate; const int* offs; const int* cnts;
};

template<int PHASE>
__global__ __launch_bounds__(256, 4)
void k_gemm(GP p)
{
  const int z  = blockIdx.z;
  const int xb = blockIdx.x;    // n-block
  const int yb = blockIdx.y;    // m-block

  int M, slotbase = 0, kbase = 0, NT, rowmode;   // 0=dense 1=listTok 2=slot
  long KD;
  const __bf16 *Ab, *Wb;
  const float* bias = nullptr;
  __bf16* hb = nullptr; int hstride = 0;
  unsigned short* pout = nullptr;
  int eidx = 0;

  if (PHASE == 1) {
    KD = C_; NT = C_ / 32;
    if (z < ES_) {
      M = NTOK; rowmode = 0; Ab = p.xns;
      Wb = p.wts + (size_t)z * H_ * C_;
      bias = p.b1s + z * H_;
      hb = p.hidws + z * H_; hstride = ES_ * H_;
    } else {
      eidx = z - ES_;
      M = p.cnts[eidx]; slotbase = p.offs[eidx]; rowmode = 1; Ab = p.xnr;
      Wb = p.wtr + (size_t)eidx * H_ * C_;
      bias = p.b1r + eidx * H_;
      hb = p.hidwr + (size_t)slotbase * H_; hstride = H_;
    }
  } else {
    if (z < 4) {
      const int kc = z;
      M = NTOK; rowmode = 0; Ab = p.hids; KD = ES_ * H_;
      kbase = kc * 2048; NT = 2048 / 32;
      Wb = p.wts; bias = (kc == 0) ? p.b2s : nullptr;
      pout = p.psh + (size_t)kc * NTOK * C_;
    } else {
      const int zz = z - 4;
      eidx = zz >> 1; const int kc = zz & 1;
      M = p.cnts[eidx]; slotbase = p.offs[eidx]; rowmode = 2; Ab = p.hidr; KD = H_;
      kbase = kc * 2048; NT = 2048 / 32;
      Wb = p.wtr + (size_t)eidx * C_ * H_;
      bias = (kc == 0) ? (p.b2r + eidx * C_) : nullptr;
      pout = p.prt + (size_t)kc * (NTOK*2) * C_ + (size_t)slotbase * C_;
    }
  }

  const int m0 = yb * 128;
  if (m0 >= M) return;
  const int n0 = xb * 128;

  const int tid = threadIdx.x;
  const int w = tid >> 6, l = tid & 63;

  __shared__ __align__(16) __bf16 Al[2 * 128 * 32];   // 16 KB
  __shared__ __align__(16) __bf16 Bl[2 * 128 * 32];   // 16 KB

  // staging: instr i covers rows i*64 + (tid>>2); 4 threads x 16B per 64B row.
  // Source k-chunk XOR-swizzled by (row>>1)&3; LDS dest linear (rule 21).
  const int sr = tid >> 2;                                // 0..63
  const int schunk = ((tid & 3) ^ ((sr >> 1) & 3)) * 8;   // elems
  const __bf16* aptr[2];
  const __bf16* bptr[2];
  #pragma unroll
  for (int i = 0; i < 2; ++i) {
    int rr = i * 64 + sr;
    int ra = m0 + rr; if (ra >= M) ra = M - 1;
    size_t arow;
    if (rowmode == 0)      arow = (size_t)ra;
    else if (rowmode == 1) arow = (size_t)p.listTok[slotbase + ra];
    else                   arow = (size_t)(slotbase + ra);
    aptr[i] = Ab + arow * KD + kbase + schunk;
    bptr[i] = Wb + (size_t)(n0 + rr) * KD + kbase + schunk;
  }

  auto stage = [&](int b, int t) {
    char* ab = (char*)Al + b * 8192 + w * 1024;
    char* bb = (char*)Bl + b * 8192 + w * 1024;
    #pragma unroll
    for (int i = 0; i < 2; ++i) {
      async_ld16(ab + i * 4096, aptr[i] + t * 32);
      async_ld16(bb + i * 4096, bptr[i] + t * 32);
    }
  };

  // fragment geometry: wave (w>>1) m-half, (w&1) n-half
  const int wm = (w >> 1) * 64;
  const int wn = (w & 1) * 64;
  const int lr = l & 15, qh = l >> 4;
  const int rchunk = (qh ^ ((lr >> 1) & 3)) * 16;   // swizzled 16B read chunk

  f32x4 acc[4][4];
  #pragma unroll
  for (int m = 0; m < 4; ++m)
    #pragma unroll
    for (int n = 0; n < 4; ++n) acc[m][n] = (f32x4){0.f, 0.f, 0.f, 0.f};

  auto compute = [&](int b) {
    const char* As = (const char*)Al + b * 8192;
    const char* Bs = (const char*)Bl + b * 8192;
    bf16x8 af[4], bfr[4];
    #pragma unroll
    for (int m = 0; m < 4; ++m)
      af[m] = *reinterpret_cast<const bf16x8*>(As + (wm + m*16 + lr) * 64 + rchunk);
    #pragma unroll
    for (int n = 0; n < 4; ++n)
      bfr[n] = *reinterpret_cast<const bf16x8*>(Bs + (wn + n*16 + lr) * 64 + rchunk);
    #pragma unroll
    for (int m = 0; m < 4; ++m)
      #pragma unroll
      for (int n = 0; n < 4; ++n)
        acc[m][n] = mfma16(af[m], bfr[n], acc[m][n]);
  };

  // ---- clean 2-phase: stage(next) || compute(cur); ONE barrier per tile ----
  stage(0, 0);
  __syncthreads();
  int bc = 0;
  for (int t = 0; t < NT; ++t) {
    if (t + 1 < NT) stage(bc ^ 1, t + 1);
    compute(bc);
    __syncthreads();
    bc ^= 1;
  }

  // ---- epilogue — C/D layout: col = lane&15, row = (lane>>4)*4 + reg ----
  #pragma unroll
  for (int mf = 0; mf < 4; ++mf) {
    const int rbase = m0 + wm + mf*16 + qh * 4;
    #pragma unroll
    for (int rg = 0; rg < 4; ++rg) {
      const int r = rbase + rg;
      if (r >= M) continue;
      if constexpr (PHASE == 1) {
        #pragma unroll
        for (int nf = 0; nf < 4; ++nf) {
          const int col = n0 + wn + nf*16 + lr;
          float v = acc[mf][nf][rg] + bias[col];
          reinterpret_cast<unsigned short*>(hb)[(size_t)r * hstride + col] =
              f2bf(gelu_f(v));
        }
      } else {
        #pragma unroll
        for (int nf = 0; nf < 4; ++nf) {
          const int col = n0 + wn + nf*16 + lr;
          float v = acc[mf][nf][rg];
          if (bias) v += bias[col];
          pout[(size_t)r * C_ + col] = f2bf(v);
        }
      }
    }
  }
}

// ------------------------------------------- final fuse: out = u + sh + routed
__global__ void k_fuse(const float* __restrict__ u,
                       const unsigned short* __restrict__ psh,
                       const unsigned short* __restrict__ prt,
                       const int* __restrict__ inv, const float* __restrict__ tkg,
                       float* __restrict__ out)
{
  const int t = blockIdx.x, tid = threadIdx.x;
  const int c = tid * 4;
  const int s0 = inv[t*2], s1 = inv[t*2+1];
  const float g0 = tkg[t*2], g1 = tkg[t*2+1];
  float4 a = reinterpret_cast<const float4*>(u + (size_t)t * C_)[tid];
  float r[4] = {a.x, a.y, a.z, a.w};
  #pragma unroll
  for (int kc = 0; kc < 4; ++kc) {
    ushort4 q = *reinterpret_cast<const ushort4*>(&psh[((size_t)kc * NTOK + t) * C_ + c]);
    r[0] += bf2f(q.x); r[1] += bf2f(q.y); r[2] += bf2f(q.z); r[3] += bf2f(q.w);
  }
  #pragma unroll
  for (int k = 0; k < 2; ++k) {
    const int s = k ? s1 : s0;
    const float g = k ? g1 : g0;
    ushort4 q0 = *reinterpret_cast<const ushort4*>(&prt[(size_t)s * C_ + c]);
    ushort4 q1 = *reinterpret_cast<const ushort4*>(&prt[((size_t)(NTOK*2) + s) * C_ + c]);
    r[0] += g * (bf2f(q0.x) + bf2f(q1.x));
    r[1] += g * (bf2f(q0.y) + bf2f(q1.y));
    r[2] += g * (bf2f(q0.z) + bf2f(q1.z));
    r[3] += g * (bf2f(q0.w) + bf2f(q1.w));
  }
  float4 o = {r[0], r[1], r[2], r[3]};
  reinterpret_cast<float4*>(out + (size_t)t * C_)[tid] = o;
}

// -----------------------------------------------------------------------------
extern "C" void kernel_launch(void* const* d_in, const int* in_sizes, int n_in,
                              void* d_out, int out_size, void* d_ws, size_t ws_size,
                              hipStream_t stream)
{
  const float* u    = (const float*)d_in[0];
  const float* gs   = (const float*)d_in[1];
  const float* W1s  = (const float*)d_in[2];
  const float* b1s  = (const float*)d_in[3];
  const float* W2s  = (const float*)d_in[4];
  const float* b2s  = (const float*)d_in[5];
  const float* gr   = (const float*)d_in[6];
  const float* W1r  = (const float*)d_in[7];
  const float* b1r  = (const float*)d_in[8];
  const float* W2r  = (const float*)d_in[9];
  const float* b2r  = (const float*)d_in[10];
  const float* cent = (const float*)d_in[11];
  float* out = (float*)d_out;

  char* ws = (char*)d_ws;
  size_t off = 0;
  auto alloc = [&](size_t bytes) -> char* {
    char* p = ws + off;
    off += (bytes + 255) & ~(size_t)255;
    return p;
  };
  __bf16* wbuf = (__bf16*)alloc((size_t)(ES_ + ER_) * H_ * C_ * 2);  // 84 MB
  __bf16* xns  = (__bf16*)alloc((size_t)NTOK * C_ * 2);
  __bf16* xnr  = (__bf16*)alloc((size_t)NTOK * C_ * 2);
  __bf16* hids = (__bf16*)alloc((size_t)NTOK * (ES_*H_) * 2);        // 33.5 MB
  __bf16* hidr = (__bf16*)alloc((size_t)NTOK * 2 * H_ * 2);          // 33.5 MB
  unsigned short* psh = (unsigned short*)alloc((size_t)4 * NTOK * C_ * 2);    // 16.8 MB
  unsigned short* prt = (unsigned short*)alloc((size_t)2 * NTOK*2 * C_ * 2);  // 16.8 MB
  int*    tki      = (int*)  alloc(NTOK * 2 * 4);
  float*  tkg      = (float*)alloc(NTOK * 2 * 4);
  int*    listTok  = (int*)  alloc(NTOK * 2 * 4);
  float*  listGate = (float*)alloc(NTOK * 2 * 4);
  int*    inv      = (int*)  alloc(NTOK * 2 * 4);
  int*    offs     = (int*)  alloc(64);
  int*    cnts     = (int*)  alloc(64);
  if (off > ws_size) {
    fprintf(stderr, "ATHENA: WORKSPACE TOO SMALL: need %zu bytes, have %zu\n", off, ws_size);
    return;
  }

  __bf16* wt_s = wbuf;
  __bf16* wt_r = wbuf + (size_t)ES_ * H_ * C_;

  GP p;
  p.xns = xns; p.xnr = xnr; p.hids = hids; p.hidr = hidr;
  p.wts = wt_s; p.wtr = wt_r;
  p.b1s = b1s; p.b1r = b1r; p.b2s = b2s; p.b2r = b2r;
  p.hidws = hids; p.hidwr = hidr;
  p.psh = psh; p.prt = prt;
  p.listTok = listTok; p.listGate = listGate; p.offs = offs; p.cnts = cnts;

  k_prep<<<dim3(NTOK), dim3(256), 0, stream>>>(u, gs, gr, cent, xns, xnr, tki, tkg);
  k_build<<<dim3(1), dim3(256), 0, stream>>>(tki, tkg, listTok, listGate, offs, cnts, inv);

  // W1 [E][C][H] -> bf16 [E*H][C]
  k_convT<<<dim3(H_/64, C_/64, ES_), dim3(256), 0, stream>>>(W1s, wt_s, C_, H_);
  k_convT<<<dim3(H_/64, C_/64, ER_), dim3(256), 0, stream>>>(W1r, wt_r, C_, H_);

  // fused GEMM1: z = {2 shared, 8 routed}; x = 32 n-blocks (H/128), y = 16 m
  k_gemm<1><<<dim3(32, 16, ES_ + ER_), dim3(256), 0, stream>>>(p);

  // W2: shared stacked [2H][C] -> [C][2H]; routed per-expert [H][C] -> [C][H]
  k_convT<<<dim3(C_/64, (ES_*H_)/64, 1), dim3(256), 0, stream>>>(W2s, wt_s, ES_*H_, C_);
  k_convT<<<dim3(C_/64, H_/64, ER_), dim3(256), 0, stream>>>(W2r, wt_r, H_, C_);

  // fused GEMM2 -> bf16 partials: z = {4 shared kc, 16 routed (e,kc)};
  // x = 8 n-blocks (C/128), y = 16 m-blocks
  k_gemm<2><<<dim3(8, 16, 4 + ER_*2), dim3(256), 0, stream>>>(p);

  // fuse: out = u + sum(psh) + g0*(prt0+prt1)[s0] + g1*(prt0+prt1)[s1]
  k_fuse<<<dim3(NTOK), dim3(256), 0, stream>>>(u, psh, prt, inv, tkg, out);
}